// Round 6
// baseline (50.676 us; speedup 1.0000x reference)
//
#include <hip/hip_runtime.h>
#include <hip/hip_bf16.h>

// Problem constants
#define BB 64
#define CC 512
#define DD 256
// loss = mean_{b,c} [ log(sum_k exp(2*S_bck)) - 2*S_bcc ],  S = Vn . Tn^T (rows L2-normalized)

typedef __attribute__((ext_vector_type(8))) short bf16x8;  // 8 bf16 = 4 VGPRs
typedef __attribute__((ext_vector_type(4))) float f32x4;

__device__ inline short f2bf(float f) {
    union { __hip_bfloat16 h; short s; } cv;
    cv.h = __float2bfloat16(f);
    return cv.s;
}

// ---------------- Pass 1: L2-normalize rows (fp32 in -> bf16 out), ~85% HBM ----------------
__global__ __launch_bounds__(256) void norm_rows(const float* __restrict__ in,
                                                 unsigned short* __restrict__ out) {
    const int row  = blockIdx.x * 4 + (threadIdx.x >> 6);
    const int lane = threadIdx.x & 63;
    const float4 x = reinterpret_cast<const float4*>(in)[(size_t)row * 64 + lane];
    float ss = x.x * x.x + x.y * x.y + x.z * x.z + x.w * x.w;
#pragma unroll
    for (int off = 32; off; off >>= 1) ss += __shfl_xor(ss, off);
    const float r = 1.0f / fmaxf(sqrtf(ss), 1e-12f);
    ushort4 o;
    o.x = (unsigned short)f2bf(x.x * r);
    o.y = (unsigned short)f2bf(x.y * r);
    o.z = (unsigned short)f2bf(x.z * r);
    o.w = (unsigned short)f2bf(x.w * r);
    reinterpret_cast<ushort4*>(out)[(size_t)row * 64 + lane] = o;
}

// ---------------- Pass 2: batched GEMM + fused loss, all-register, zero in-loop barriers ----
// 512 blocks = 64 batches x 8 row-blocks of 64 V-rows; 4 waves; no LDS except final reduce.
// Both operands are pre-normalized bf16 (L3-resident after pass 1). Each wave:
//  - caches its A fragments a[4][8] (64 rows x K=256) straight from global,
//  - owns 16 output columns per 64-col tile -> needs only T rows ct*64+wave*16+ln,
//    loaded as register fragments, trickle-prefetched one tile ahead (T14-style),
//  - accumulates rowsum(exp(2S)) and the diagonal term in registers.
// Waves run completely desynchronized (setprio around MFMA pays per T5).
__global__ __launch_bounds__(256, 2) void gemm_loss(const unsigned short* __restrict__ Vn,
                                                    const unsigned short* __restrict__ Tn,
                                                    float* __restrict__ partials) {
    __shared__ float vred[256];  // [64 rows][4 waves] partial exp-sums
    __shared__ float dred[256];  // [64 rows][4 waves] partial diag terms

    // XCD-aware remap: the 8 row-blocks of one batch land on one XCD (T panel L2 reuse)
    const int i0 = blockIdx.x;
    const int b  = (i0 & 7) * 8 + ((i0 >> 3) & 7);
    const int rb = i0 >> 6;

    const int tid  = threadIdx.x;
    const int lane = tid & 63;
    const int wave = tid >> 6;   // each wave owns cols [ct*64 + wave*16, +16) of every tile
    const int g    = lane >> 4;  // k-group 0..3
    const int ln   = lane & 15;

    const char* gA = reinterpret_cast<const char*>(Vn + (size_t)b * (CC * DD) + (size_t)rb * 64 * DD);
    const char* gB = reinterpret_cast<const char*>(Tn + (size_t)b * (CC * DD));

    // ---- cache A fragments in registers (rows i*16+ln, 16B chunks at kk*64+g*16) ----
    bf16x8 a[4][8];
#pragma unroll
    for (int i = 0; i < 4; ++i) {
        const char* rp = gA + (i * 16 + ln) * 512 + g * 16;
#pragma unroll
        for (int kk = 0; kk < 8; ++kk)
            a[i][kk] = *reinterpret_cast<const bf16x8*>(rp + kk * 64);
    }

    // ---- load B tile 0 fragments (T rows wave*16+ln) ----
    const char* rpB = gB + (wave * 16 + ln) * 512 + g * 16;  // tile ct: + ct*32768
    bf16x8 bb[8];
#pragma unroll
    for (int kk = 0; kk < 8; ++kk)
        bb[kk] = *reinterpret_cast<const bf16x8*>(rpB + kk * 64);

    float rs[4][4];  // rowsum of exp(2S) over this wave's 16-col slices
    float dg[4][4];  // diagonal 2*S term
#pragma unroll
    for (int i = 0; i < 4; ++i)
#pragma unroll
        for (int r = 0; r < 4; ++r) { rs[i][r] = 0.f; dg[i][r] = 0.f; }

    for (int ct = 0; ct < 8; ++ct) {
        f32x4 acc[4];
#pragma unroll
        for (int i = 0; i < 4; ++i) acc[i] = (f32x4){0.f, 0.f, 0.f, 0.f};

        __builtin_amdgcn_s_setprio(1);
#pragma unroll
        for (int kk = 0; kk < 8; ++kk) {
#pragma unroll
            for (int i = 0; i < 4; ++i)
                acc[i] = __builtin_amdgcn_mfma_f32_16x16x32_bf16(a[i][kk], bb[kk], acc[i], 0, 0, 0);
            // trickle-prefetch next tile's fragment into the slot just consumed;
            // the 8 loads stay in flight across the exp epilogue below
            if (ct < 7)
                bb[kk] = *reinterpret_cast<const bf16x8*>(rpB + (ct + 1) * 32768 + kk * 64);
        }
        __builtin_amdgcn_s_setprio(0);

        // ---- fused epilogue: exp(2*S) partial rowsum + diagonal grab ----
        const int gcol = ct * 64 + wave * 16 + ln;  // global col of this lane's acc slice
#pragma unroll
        for (int i = 0; i < 4; ++i) {
            const int grow = rb * 64 + i * 16 + g * 4;  // global row (+r)
#pragma unroll
            for (int r = 0; r < 4; ++r) {
                const float s2 = acc[i][r] * 2.0f;  // sim / TEMPERATURE
                rs[i][r] += __expf(s2);
                if (gcol == grow + r) dg[i][r] += s2;
            }
        }
    }

    // ---- per-row completion: combine the 4 waves' exp-sums BEFORE log ----
#pragma unroll
    for (int i = 0; i < 4; ++i)
#pragma unroll
        for (int r = 0; r < 4; ++r) {
            float v = rs[i][r];
            float d = dg[i][r];
#pragma unroll
            for (int m = 1; m < 16; m <<= 1) {  // reduce the 16 column-lanes
                v += __shfl_xor(v, m);
                d += __shfl_xor(d, m);
            }
            if (ln == 0) {
                const int rl = i * 16 + g * 4 + r;  // local row 0..63
                vred[rl * 4 + wave] = v;
                dred[rl * 4 + wave] = d;
            }
        }
    __syncthreads();

    if (wave == 0) {
        const float vv =
            vred[lane * 4] + vred[lane * 4 + 1] + vred[lane * 4 + 2] + vred[lane * 4 + 3];
        const float dd =
            dred[lane * 4] + dred[lane * 4 + 1] + dred[lane * 4 + 2] + dred[lane * 4 + 3];
        float lsum = logf(vv) - dd;
#pragma unroll
        for (int m = 1; m < 64; m <<= 1) lsum += __shfl_xor(lsum, m);
        if (lane == 0) partials[i0] = lsum;
    }
}

// ---------------- Pass 3: final deterministic reduce (512 partials) ----------------
__global__ __launch_bounds__(256) void final_reduce(const float* __restrict__ partials,
                                                    float* __restrict__ out) {
    const int t = threadIdx.x;
    float v = partials[t] + partials[t + 256];
#pragma unroll
    for (int m = 1; m < 64; m <<= 1) v += __shfl_xor(v, m);
    __shared__ float red[4];
    if ((t & 63) == 0) red[t >> 6] = v;
    __syncthreads();
    if (t == 0) out[0] = (red[0] + red[1] + red[2] + red[3]) * (1.0f / 32768.0f);
}

extern "C" void kernel_launch(void* const* d_in, const int* in_sizes, int n_in,
                              void* d_out, int out_size, void* d_ws, size_t ws_size,
                              hipStream_t stream) {
    const float* vis = (const float*)d_in[0];
    const float* txt = (const float*)d_in[1];

    unsigned short* Vn = (unsigned short*)d_ws;                 // 64*512*256 bf16 = 16.8 MB
    unsigned short* Tn = Vn + (size_t)BB * CC * DD;             // +16.8 MB
    float* partials    = (float*)(Tn + (size_t)BB * CC * DD);   // 512 floats
    float* out         = (float*)d_out;

    norm_rows<<<8192, 256, 0, stream>>>(vis, Vn);
    norm_rows<<<8192, 256, 0, stream>>>(txt, Tn);
    gemm_loss<<<512, 256, 0, stream>>>(Vn, Tn, partials);
    final_reduce<<<1, 256, 0, stream>>>(partials, out);
}

// Round 7
// 44.826 us; speedup vs baseline: 1.1305x; 1.1305x over previous
//
#include <hip/hip_runtime.h>
#include <hip/hip_bf16.h>

// Problem constants
#define BB 64
#define CC 512
#define DD 256
// loss = mean_{b,c} [ log(sum_k exp(2*S_bck)) - 2*S_bcc ],  S = Vn . Tn^T (rows L2-normalized)

typedef __attribute__((ext_vector_type(8))) short bf16x8;  // 8 bf16 = 4 VGPRs
typedef __attribute__((ext_vector_type(4))) float f32x4;
typedef unsigned int u32;

#define SWZ(r) (((r) & 7) << 4)

__device__ inline short f2bf(float f) {
    union { __hip_bfloat16 h; short s; } cv;
    cv.h = __float2bfloat16(f);
    return cv.s;
}

// ---------------- Pass 1: L2-normalize T rows (fp32 in -> bf16 out), ~85% HBM ----------------
__global__ __launch_bounds__(256) void norm_rows(const float* __restrict__ in,
                                                 unsigned short* __restrict__ out) {
    const int row  = blockIdx.x * 4 + (threadIdx.x >> 6);
    const int lane = threadIdx.x & 63;
    const float4 x = reinterpret_cast<const float4*>(in)[(size_t)row * 64 + lane];
    float ss = x.x * x.x + x.y * x.y + x.z * x.z + x.w * x.w;
#pragma unroll
    for (int off = 32; off; off >>= 1) ss += __shfl_xor(ss, off);
    const float r = 1.0f / fmaxf(sqrtf(ss), 1e-12f);
    ushort4 o;
    o.x = (unsigned short)f2bf(x.x * r);
    o.y = (unsigned short)f2bf(x.y * r);
    o.z = (unsigned short)f2bf(x.z * r);
    o.w = (unsigned short)f2bf(x.w * r);
    reinterpret_cast<ushort4*>(out)[(size_t)row * 64 + lane] = o;
}

// ---------------- Pass 2: fused V-norm + GEMM + loss, per-wave private pipelines ----------------
// 512 blocks = 64 batches x 8 row-blocks of 64 V-rows; 4 waves; 66 KiB LDS (2 blocks/CU).
// Each wave owns output cols [ct*64+wave*16, +16) of every tile -> it needs ONLY B rows
// wave*16+ln of each tile, which it stages itself via global_load_lds into a PRIVATE
// double-buffered 2x8KB LDS slice. No cross-wave B sharing => ZERO in-loop barriers.
// Tile landing enforced by counted inline-asm s_waitcnt vmcnt(8) (next tile's 8 loads stay
// in flight across ds_read+MFMA+exp). A (64 fp32 V rows) is normalized in the prologue,
// routed via LDS, cached in regs a[4][8].
__global__ __launch_bounds__(256, 2) void gemm_loss(const float* __restrict__ V,
                                                    const unsigned short* __restrict__ Tn,
                                                    float* __restrict__ partials) {
    __shared__ char lds[65536];   // buf0 = lds+0, buf1 = lds+32768; wave slice = +wave*8192
    __shared__ float vred[256];   // [64 rows][4 waves] partial exp-sums (separate: no race
    __shared__ float dred[256];   //  with desynced waves still reading tile buffers)

    // XCD-aware remap: the 8 row-blocks of one batch land on one XCD (T panel L2 reuse)
    const int i0 = blockIdx.x;
    const int b  = (i0 & 7) * 8 + ((i0 >> 3) & 7);
    const int rb = i0 >> 6;

    const int tid  = threadIdx.x;
    const int lane = tid & 63;
    const int wave = tid >> 6;
    const int g    = lane >> 4;  // k-group 0..3
    const int ln   = lane & 15;

    const float* gV = V + (size_t)b * (CC * DD) + (size_t)rb * 64 * DD;
    const char*  gT = reinterpret_cast<const char*>(Tn + (size_t)b * (CC * DD));  // 512 B rows

    // ---- issue async DMA: tile 0 (B rows wave*16..+15) -> wave's buf0 slice ----
#pragma unroll
    for (int r2 = 0; r2 < 8; ++r2) {
        const int L  = r2 * 1024 + (lane << 4);
        const int lr = L >> 9, inrow = L & 511;
        __builtin_amdgcn_global_load_lds(
            (const u32*)(gT + (size_t)(wave * 16 + lr) * 512 + (inrow ^ SWZ(lr))),
            (u32*)(lds + wave * 8192 + r2 * 1024), 16, 0, 0);
    }

    // ---- A prologue: load 64 fp32 V rows, L2-normalize, write bf16 swizzled into buf1 ----
    {
        const int rrow  = tid >> 3;        // 8 threads/row, 32 rows/pass
        const int ecolB = (tid & 7) * 64;  // byte offset of this thread's 32 bf16 elems
        char* bufA = lds + 32768;
#pragma unroll
        for (int p = 0; p < 2; ++p) {
            const float4* src =
                reinterpret_cast<const float4*>(gV + (size_t)(p * 32 + rrow) * DD) + (tid & 7) * 8;
            float4 x[8];
#pragma unroll
            for (int q = 0; q < 8; ++q) x[q] = src[q];
            float ss = 0.f;
#pragma unroll
            for (int q = 0; q < 8; ++q)
                ss += x[q].x * x[q].x + x[q].y * x[q].y + x[q].z * x[q].z + x[q].w * x[q].w;
            ss += __shfl_xor(ss, 1);
            ss += __shfl_xor(ss, 2);
            ss += __shfl_xor(ss, 4);  // 8 lanes own the row
            const float rinv = 1.0f / fmaxf(sqrtf(ss), 1e-12f);
            const int row = p * 32 + rrow;
            char* dstrow  = bufA + row * 512;
            const int sw  = SWZ(row);
#pragma unroll
            for (int q2 = 0; q2 < 4; ++q2) {
                const float4 v0 = x[2 * q2], v1 = x[2 * q2 + 1];
                bf16x8 o;
                o[0] = f2bf(v0.x * rinv); o[1] = f2bf(v0.y * rinv);
                o[2] = f2bf(v0.z * rinv); o[3] = f2bf(v0.w * rinv);
                o[4] = f2bf(v1.x * rinv); o[5] = f2bf(v1.y * rinv);
                o[6] = f2bf(v1.z * rinv); o[7] = f2bf(v1.w * rinv);
                *reinterpret_cast<bf16x8*>(dstrow + ((ecolB + q2 * 16) ^ sw)) = o;
            }
        }
    }
    __syncthreads();  // A visible to all waves (also drains tile0 DMA - harmless)

    // ---- cache A fragments in registers (a[4][8] = 128 VGPR; cross-wave reads) ----
    bf16x8 a[4][8];
#pragma unroll
    for (int i = 0; i < 4; ++i) {
        const int row  = i * 16 + ln;
        const char* rp = lds + 32768 + row * 512;
        const int sw   = SWZ(row);
#pragma unroll
        for (int kk = 0; kk < 8; ++kk)
            a[i][kk] = *reinterpret_cast<const bf16x8*>(rp + ((kk * 64 + g * 16) ^ sw));
    }
    __syncthreads();  // all a[] reads done -> buf1 free for tile 1 DMA; vmcnt clean

    float rs[4][4];  // rowsum of exp(2S) over this wave's 16-col slices
    float dg[4][4];  // diagonal 2*S term
#pragma unroll
    for (int i = 0; i < 4; ++i)
#pragma unroll
        for (int r = 0; r < 4; ++r) { rs[i][r] = 0.f; dg[i][r] = 0.f; }

#pragma unroll
    for (int ct = 0; ct < 8; ++ct) {
        // ---- issue next tile's 8 private DMA loads, then counted wait for current tile ----
        if (ct < 7) {
            const char* gtile = gT + (size_t)(ct + 1) * 64 * 512;
            char* dst = lds + (((ct + 1) & 1) ? 32768 : 0) + wave * 8192;
#pragma unroll
            for (int r2 = 0; r2 < 8; ++r2) {
                const int L  = r2 * 1024 + (lane << 4);
                const int lr = L >> 9, inrow = L & 511;
                __builtin_amdgcn_global_load_lds(
                    (const u32*)(gtile + (size_t)(ct * 64 + 64 + wave * 16 + lr) * 512 * 0 +
                                 (size_t)(wave * 16 + lr) * 512 + (inrow ^ SWZ(lr))),
                    (u32*)(dst + r2 * 1024), 16, 0, 0);
            }
            asm volatile("s_waitcnt vmcnt(8)" ::: "memory");  // oldest 8 (tile ct) landed
        } else {
            asm volatile("s_waitcnt vmcnt(0)" ::: "memory");  // last tile: drain
        }
        __builtin_amdgcn_sched_barrier(0);

        // ---- ds_read this wave's 8 B fragments (private slice, 2-way max conflicts) ----
        const char* Bc = lds + ((ct & 1) ? 32768 : 0) + wave * 8192;
        const char* rp = Bc + ln * 512;
        const int sw   = SWZ(ln);
        bf16x8 bb[8];
#pragma unroll
        for (int kk = 0; kk < 8; ++kk)
            bb[kk] = *reinterpret_cast<const bf16x8*>(rp + ((kk * 64 + g * 16) ^ sw));

        // ---- 32 MFMA ----
        f32x4 acc[4];
#pragma unroll
        for (int i = 0; i < 4; ++i) acc[i] = (f32x4){0.f, 0.f, 0.f, 0.f};
        __builtin_amdgcn_s_setprio(1);
#pragma unroll
        for (int kk = 0; kk < 8; ++kk)
#pragma unroll
            for (int i = 0; i < 4; ++i)
                acc[i] = __builtin_amdgcn_mfma_f32_16x16x32_bf16(a[i][kk], bb[kk], acc[i], 0, 0, 0);
        __builtin_amdgcn_s_setprio(0);

        // ---- fused epilogue: exp(2*S) partial rowsum (+ diagonal only in tile ct==rb) ----
        const int gcol = ct * 64 + wave * 16 + ln;
#pragma unroll
        for (int i = 0; i < 4; ++i) {
            const int grow = rb * 64 + i * 16 + g * 4;  // + r
#pragma unroll
            for (int r = 0; r < 4; ++r) {
                const float s2 = acc[i][r] * 2.0f;  // sim / TEMPERATURE
                rs[i][r] += __expf(s2);
                if (ct == rb && gcol == grow + r) dg[i][r] += s2;
            }
        }
    }

    // ---- per-row completion: combine the 4 waves' exp-sums BEFORE log ----
#pragma unroll
    for (int i = 0; i < 4; ++i)
#pragma unroll
        for (int r = 0; r < 4; ++r) {
            float v = rs[i][r];
            float d = dg[i][r];
#pragma unroll
            for (int m = 1; m < 16; m <<= 1) {  // reduce the 16 column-lanes
                v += __shfl_xor(v, m);
                d += __shfl_xor(d, m);
            }
            if (ln == 0) {
                const int rl = i * 16 + g * 4 + r;  // local row 0..63
                vred[rl * 4 + wave] = v;
                dred[rl * 4 + wave] = d;
            }
        }
    __syncthreads();

    if (wave == 0) {
        const float vv =
            vred[lane * 4] + vred[lane * 4 + 1] + vred[lane * 4 + 2] + vred[lane * 4 + 3];
        const float dd =
            dred[lane * 4] + dred[lane * 4 + 1] + dred[lane * 4 + 2] + dred[lane * 4 + 3];
        float lsum = logf(vv) - dd;
#pragma unroll
        for (int m = 1; m < 64; m <<= 1) lsum += __shfl_xor(lsum, m);
        if (lane == 0) partials[i0] = lsum;
    }
}

// ---------------- Pass 3: final deterministic reduce (512 partials) ----------------
__global__ __launch_bounds__(256) void final_reduce(const float* __restrict__ partials,
                                                    float* __restrict__ out) {
    const int t = threadIdx.x;
    float v = partials[t] + partials[t + 256];
#pragma unroll
    for (int m = 1; m < 64; m <<= 1) v += __shfl_xor(v, m);
    __shared__ float red[4];
    if ((t & 63) == 0) red[t >> 6] = v;
    __syncthreads();
    if (t == 0) out[0] = (red[0] + red[1] + red[2] + red[3]) * (1.0f / 32768.0f);
}

extern "C" void kernel_launch(void* const* d_in, const int* in_sizes, int n_in,
                              void* d_out, int out_size, void* d_ws, size_t ws_size,
                              hipStream_t stream) {
    const float* vis = (const float*)d_in[0];
    const float* txt = (const float*)d_in[1];

    unsigned short* Tn = (unsigned short*)d_ws;                             // 16.8 MB
    float* partials    = (float*)((char*)d_ws + (size_t)BB * CC * DD * 2);  // 512 floats
    float* out         = (float*)d_out;

    norm_rows<<<8192, 256, 0, stream>>>(txt, Tn);
    gemm_loss<<<512, 256, 0, stream>>>(vis, Tn, partials);
    final_reduce<<<1, 256, 0, stream>>>(partials, out);
}

// Round 8
// 40.567 us; speedup vs baseline: 1.2492x; 1.1050x over previous
//
#include <hip/hip_runtime.h>
#include <hip/hip_bf16.h>

// Problem constants
#define BB 64
#define CC 512
#define DD 256
// loss = mean_{b,c} [ log(sum_k exp(2*S_bck)) - 2*S_bcc ],  S = Vn . Tn^T (rows L2-normalized)

typedef __attribute__((ext_vector_type(8))) short bf16x8;  // 8 bf16 = 4 VGPRs
typedef __attribute__((ext_vector_type(4))) float f32x4;
typedef unsigned int u32;

#define SWZ(r) (((r) & 7) << 4)

__device__ inline short f2bf(float f) {
    union { __hip_bfloat16 h; short s; } cv;
    cv.h = __float2bfloat16(f);
    return cv.s;
}

// ---------------- Pass 1: L2-normalize T rows (fp32 in -> bf16 out), ~85% HBM ----------------
__global__ __launch_bounds__(256) void norm_rows(const float* __restrict__ in,
                                                 unsigned short* __restrict__ out) {
    const int row  = blockIdx.x * 4 + (threadIdx.x >> 6);
    const int lane = threadIdx.x & 63;
    const float4 x = reinterpret_cast<const float4*>(in)[(size_t)row * 64 + lane];
    float ss = x.x * x.x + x.y * x.y + x.z * x.z + x.w * x.w;
#pragma unroll
    for (int off = 32; off; off >>= 1) ss += __shfl_xor(ss, off);
    const float r = 1.0f / fmaxf(sqrtf(ss), 1e-12f);
    ushort4 o;
    o.x = (unsigned short)f2bf(x.x * r);
    o.y = (unsigned short)f2bf(x.y * r);
    o.z = (unsigned short)f2bf(x.z * r);
    o.w = (unsigned short)f2bf(x.w * r);
    reinterpret_cast<ushort4*>(out)[(size_t)row * 64 + lane] = o;
}

// ---------------- Pass 2: fused V-norm + GEMM + loss, per-wave private pipelines ----------------
// 512 blocks = 64 batches x 8 row-blocks of 64 V-rows; 4 waves; ~66 KiB LDS (2 blocks/CU).
// Each wave owns output cols [ct*64+wave*16, +16) of every tile -> it needs ONLY B rows
// wave*16+ln of each tile, staged by itself via global_load_lds into a PRIVATE
// double-buffered 2x8KB LDS slice. No cross-wave B sharing => ZERO in-loop barriers;
// tile landing is enforced by counted s_waitcnt vmcnt(8) (next tile's 8 loads stay in
// flight across ds_read+MFMA+exp; never drained mid-loop). A (64 fp32 V rows) is
// normalized in the prologue, routed via LDS buf1, cached in regs a[4][8].
// NOTE: ct-loop deliberately NOT unrolled (R7's unroll caused 30 MB scratch spill).
__global__ __launch_bounds__(256, 2) void gemm_loss(const float* __restrict__ V,
                                                    const unsigned short* __restrict__ Tn,
                                                    float* __restrict__ partials) {
    __shared__ char lds[65536];   // buf0 = lds+0, buf1 = lds+32768; wave slice = +wave*8192
    __shared__ float vred[256];   // [64 rows][4 waves] partial exp-sums
    __shared__ float dred[256];   // [64 rows][4 waves] partial diag terms

    // XCD-aware remap: the 8 row-blocks of one batch land on one XCD (T panel L2 reuse)
    const int i0 = blockIdx.x;
    const int b  = (i0 & 7) * 8 + ((i0 >> 3) & 7);
    const int rb = i0 >> 6;

    const int tid  = threadIdx.x;
    const int lane = tid & 63;
    const int wave = tid >> 6;
    const int g    = lane >> 4;  // k-group 0..3
    const int ln   = lane & 15;

    const float* gV = V + (size_t)b * (CC * DD) + (size_t)rb * 64 * DD;
    const char*  gT = reinterpret_cast<const char*>(Tn + (size_t)b * (CC * DD));  // 512 B rows

    // ---- issue async DMA: tile 0 (B rows wave*16..+15) -> wave's buf0 slice ----
#pragma unroll
    for (int r2 = 0; r2 < 8; ++r2) {
        const int L  = r2 * 1024 + (lane << 4);
        const int lr = L >> 9, inrow = L & 511;
        __builtin_amdgcn_global_load_lds(
            (const u32*)(gT + (size_t)(wave * 16 + lr) * 512 + (inrow ^ SWZ(lr))),
            (u32*)(lds + wave * 8192 + r2 * 1024), 16, 0, 0);
    }

    // ---- A prologue: load 64 fp32 V rows, L2-normalize, write bf16 swizzled into buf1 ----
    {
        const int rrow  = tid >> 3;        // 8 threads/row, 32 rows/pass
        const int ecolB = (tid & 7) * 64;  // byte offset of this thread's 32 bf16 elems
        char* bufA = lds + 32768;
#pragma unroll
        for (int p = 0; p < 2; ++p) {
            const float4* src =
                reinterpret_cast<const float4*>(gV + (size_t)(p * 32 + rrow) * DD) + (tid & 7) * 8;
            float4 x[8];
#pragma unroll
            for (int q = 0; q < 8; ++q) x[q] = src[q];
            float ss = 0.f;
#pragma unroll
            for (int q = 0; q < 8; ++q)
                ss += x[q].x * x[q].x + x[q].y * x[q].y + x[q].z * x[q].z + x[q].w * x[q].w;
            ss += __shfl_xor(ss, 1);
            ss += __shfl_xor(ss, 2);
            ss += __shfl_xor(ss, 4);  // 8 lanes own the row
            const float rinv = 1.0f / fmaxf(sqrtf(ss), 1e-12f);
            const int row = p * 32 + rrow;
            char* dstrow  = bufA + row * 512;
            const int sw  = SWZ(row);
#pragma unroll
            for (int q2 = 0; q2 < 4; ++q2) {
                const float4 v0 = x[2 * q2], v1 = x[2 * q2 + 1];
                bf16x8 o;
                o[0] = f2bf(v0.x * rinv); o[1] = f2bf(v0.y * rinv);
                o[2] = f2bf(v0.z * rinv); o[3] = f2bf(v0.w * rinv);
                o[4] = f2bf(v1.x * rinv); o[5] = f2bf(v1.y * rinv);
                o[6] = f2bf(v1.z * rinv); o[7] = f2bf(v1.w * rinv);
                *reinterpret_cast<bf16x8*>(dstrow + ((ecolB + q2 * 16) ^ sw)) = o;
            }
        }
    }
    __syncthreads();  // A visible to all waves (implicit vmcnt(0) also lands tile-0 DMA)

    // ---- cache A fragments in registers (a[4][8] = 128 VGPR; cross-wave reads) ----
    bf16x8 a[4][8];
#pragma unroll
    for (int i = 0; i < 4; ++i) {
        const int row  = i * 16 + ln;
        const char* rp = lds + 32768 + row * 512;
        const int sw   = SWZ(row);
#pragma unroll
        for (int kk = 0; kk < 8; ++kk)
            a[i][kk] = *reinterpret_cast<const bf16x8*>(rp + ((kk * 64 + g * 16) ^ sw));
    }
    __syncthreads();  // all a[] reads done -> buf1 free for tile-1 DMA

    float rs[4][4];  // rowsum of exp(2S) over this wave's 16-col slices
    float dg[4][4];  // diagonal 2*S term
#pragma unroll
    for (int i = 0; i < 4; ++i)
#pragma unroll
        for (int r = 0; r < 4; ++r) { rs[i][r] = 0.f; dg[i][r] = 0.f; }

    for (int ct = 0; ct < 8; ++ct) {  // NOT unrolled (register pressure)
        // ---- issue next tile's 8 private DMA loads, then counted wait for current tile ----
        if (ct < 7) {
            const char* gtile = gT + (size_t)(ct + 1) * 64 * 512;
            char* dst = lds + (((ct + 1) & 1) ? 32768 : 0) + wave * 8192;
#pragma unroll
            for (int r2 = 0; r2 < 8; ++r2) {
                const int L  = r2 * 1024 + (lane << 4);
                const int lr = L >> 9, inrow = L & 511;
                __builtin_amdgcn_global_load_lds(
                    (const u32*)(gtile + (size_t)(wave * 16 + lr) * 512 + (inrow ^ SWZ(lr))),
                    (u32*)(dst + r2 * 1024), 16, 0, 0);
            }
            asm volatile("s_waitcnt vmcnt(8)" ::: "memory");  // oldest 8 (tile ct) landed
        } else {
            asm volatile("s_waitcnt vmcnt(0)" ::: "memory");  // last tile: drain
        }

        // ---- ds_read (just-in-time, per kk) + 32 MFMA ----
        const char* rp = lds + ((ct & 1) ? 32768 : 0) + wave * 8192 + ln * 512;
        const int sw   = SWZ(ln);
        f32x4 acc[4];
#pragma unroll
        for (int i = 0; i < 4; ++i) acc[i] = (f32x4){0.f, 0.f, 0.f, 0.f};
        __builtin_amdgcn_s_setprio(1);
#pragma unroll
        for (int kk = 0; kk < 8; ++kk) {
            const bf16x8 bb = *reinterpret_cast<const bf16x8*>(rp + ((kk * 64 + g * 16) ^ sw));
#pragma unroll
            for (int i = 0; i < 4; ++i)
                acc[i] = __builtin_amdgcn_mfma_f32_16x16x32_bf16(a[i][kk], bb, acc[i], 0, 0, 0);
        }
        __builtin_amdgcn_s_setprio(0);

        // ---- fused epilogue: exp(2*S) partial rowsum (+ diagonal only in tile ct==rb) ----
        const int gcol = ct * 64 + wave * 16 + ln;
#pragma unroll
        for (int i = 0; i < 4; ++i) {
            const int grow = rb * 64 + i * 16 + g * 4;  // + r
#pragma unroll
            for (int r = 0; r < 4; ++r) {
                const float s2 = acc[i][r] * 2.0f;  // sim / TEMPERATURE
                rs[i][r] += __expf(s2);
                if (ct == rb && gcol == grow + r) dg[i][r] += s2;
            }
        }
    }

    // ---- per-row completion: combine the 4 waves' exp-sums BEFORE log ----
#pragma unroll
    for (int i = 0; i < 4; ++i)
#pragma unroll
        for (int r = 0; r < 4; ++r) {
            float v = rs[i][r];
            float d = dg[i][r];
#pragma unroll
            for (int m = 1; m < 16; m <<= 1) {  // reduce the 16 column-lanes
                v += __shfl_xor(v, m);
                d += __shfl_xor(d, m);
            }
            if (ln == 0) {
                const int rl = i * 16 + g * 4 + r;  // local row 0..63
                vred[rl * 4 + wave] = v;
                dred[rl * 4 + wave] = d;
            }
        }
    __syncthreads();

    if (wave == 0) {
        const float vv =
            vred[lane * 4] + vred[lane * 4 + 1] + vred[lane * 4 + 2] + vred[lane * 4 + 3];
        const float dd =
            dred[lane * 4] + dred[lane * 4 + 1] + dred[lane * 4 + 2] + dred[lane * 4 + 3];
        float lsum = logf(vv) - dd;
#pragma unroll
        for (int m = 1; m < 64; m <<= 1) lsum += __shfl_xor(lsum, m);
        if (lane == 0) partials[i0] = lsum;
    }
}

// ---------------- Pass 3: final deterministic reduce (512 partials) ----------------
__global__ __launch_bounds__(256) void final_reduce(const float* __restrict__ partials,
                                                    float* __restrict__ out) {
    const int t = threadIdx.x;
    float v = partials[t] + partials[t + 256];
#pragma unroll
    for (int m = 1; m < 64; m <<= 1) v += __shfl_xor(v, m);
    __shared__ float red[4];
    if ((t & 63) == 0) red[t >> 6] = v;
    __syncthreads();
    if (t == 0) out[0] = (red[0] + red[1] + red[2] + red[3]) * (1.0f / 32768.0f);
}

extern "C" void kernel_launch(void* const* d_in, const int* in_sizes, int n_in,
                              void* d_out, int out_size, void* d_ws, size_t ws_size,
                              hipStream_t stream) {
    const float* vis = (const float*)d_in[0];
    const float* txt = (const float*)d_in[1];

    unsigned short* Tn = (unsigned short*)d_ws;                             // 16.8 MB
    float* partials    = (float*)((char*)d_ws + (size_t)BB * CC * DD * 2);  // 512 floats
    float* out         = (float*)d_out;

    norm_rows<<<8192, 256, 0, stream>>>(txt, Tn);
    gemm_loss<<<512, 256, 0, stream>>>(vis, Tn, partials);
    final_reduce<<<1, 256, 0, stream>>>(partials, out);
}

// Round 9
// 40.466 us; speedup vs baseline: 1.2523x; 1.0025x over previous
//
#include <hip/hip_runtime.h>
#include <hip/hip_bf16.h>

// Problem constants
#define BB 64
#define CC 512
#define DD 256
// loss = mean_{b,c} [ log(sum_k exp(2*S_bck)) - 2*S_bcc ],  S = Vn . Tn^T (rows L2-normalized)

typedef __attribute__((ext_vector_type(8))) short bf16x8;  // 8 bf16 = 4 VGPRs
typedef __attribute__((ext_vector_type(4))) float f32x4;
typedef unsigned int u32;

#define SWZ(r) (((r) & 7) << 4)

__device__ inline short f2bf(float f) {
    union { __hip_bfloat16 h; short s; } cv;
    cv.h = __float2bfloat16(f);
    return cv.s;
}

// ---------------- Pass 1: L2-normalize T rows (fp32 in -> bf16 out), ~85% HBM ----------------
__global__ __launch_bounds__(256) void norm_rows(const float* __restrict__ in,
                                                 unsigned short* __restrict__ out) {
    const int row  = blockIdx.x * 4 + (threadIdx.x >> 6);
    const int lane = threadIdx.x & 63;
    const float4 x = reinterpret_cast<const float4*>(in)[(size_t)row * 64 + lane];
    float ss = x.x * x.x + x.y * x.y + x.z * x.z + x.w * x.w;
#pragma unroll
    for (int off = 32; off; off >>= 1) ss += __shfl_xor(ss, off);
    const float r = 1.0f / fmaxf(sqrtf(ss), 1e-12f);
    ushort4 o;
    o.x = (unsigned short)f2bf(x.x * r);
    o.y = (unsigned short)f2bf(x.y * r);
    o.z = (unsigned short)f2bf(x.z * r);
    o.w = (unsigned short)f2bf(x.w * r);
    reinterpret_cast<ushort4*>(out)[(size_t)row * 64 + lane] = o;
}

// ---------------- Pass 2: fused V-norm + GEMM + loss, HIGH-OCCUPANCY version ----------------
// 512 blocks = 64 batches x 8 row-blocks of 64 V-rows; 4 waves; 34 KiB LDS; regs <= 128
// => 4 blocks/CU x 4 waves = 16 waves/CU (4/SIMD) — 2x R8. Wave (wr,wc) owns a 32-row x
// 16-col slice of each 32-col B tile: a[2][8] = 64 VGPR only. B tiles (32 T-rows, 16 KB)
// staged 2-ahead via global_load_lds (pre-swizzled source), consumed under raw s_barrier +
// counted s_waitcnt vmcnt(4) — the in-flight prefetch is NEVER drained mid-loop.
__global__ __launch_bounds__(256, 4) void gemm_loss(const float* __restrict__ V,
                                                    const unsigned short* __restrict__ Tn,
                                                    float* __restrict__ partials) {
    __shared__ char ldsb[32768];  // dbuf: buf0=[0,16K), buf1=[16K,32K); prologue: A staging
    __shared__ float vred[128];   // [64 rows][2 wc] partial exp-sums
    __shared__ float dred[128];   // [64 rows][2 wc] partial diag terms

    // XCD-aware remap: the 8 row-blocks of one batch land on one XCD (T panel L2 reuse)
    const int i0 = blockIdx.x;
    const int b  = (i0 & 7) * 8 + ((i0 >> 3) & 7);
    const int rb = i0 >> 6;

    const int tid  = threadIdx.x;
    const int lane = tid & 63;
    const int wave = tid >> 6;
    const int wr   = wave >> 1;  // row half (32 rows)
    const int wc   = wave & 1;   // col half (16 of 32 tile cols)
    const int g    = lane >> 4;  // k-group 0..3
    const int ln   = lane & 15;

    const float* gV = V + (size_t)b * (CC * DD) + (size_t)rb * 64 * DD;
    const char*  gT = reinterpret_cast<const char*>(Tn + (size_t)b * (CC * DD));  // 512 B rows

    // ---- A prologue: load 64 fp32 V rows, L2-normalize, write bf16 swizzled into ldsb ----
    {
        const int rrow  = tid >> 3;        // 8 threads/row, 32 rows/pass
        const int ecolB = (tid & 7) * 64;  // byte offset of this thread's 32 bf16 elems
#pragma unroll
        for (int p = 0; p < 2; ++p) {
            const float4* src =
                reinterpret_cast<const float4*>(gV + (size_t)(p * 32 + rrow) * DD) + (tid & 7) * 8;
            float4 x[8];
#pragma unroll
            for (int q = 0; q < 8; ++q) x[q] = src[q];
            float ss = 0.f;
#pragma unroll
            for (int q = 0; q < 8; ++q)
                ss += x[q].x * x[q].x + x[q].y * x[q].y + x[q].z * x[q].z + x[q].w * x[q].w;
            ss += __shfl_xor(ss, 1);
            ss += __shfl_xor(ss, 2);
            ss += __shfl_xor(ss, 4);  // 8 lanes own the row
            const float rinv = 1.0f / fmaxf(sqrtf(ss), 1e-12f);
            const int row = p * 32 + rrow;
            char* dstrow  = ldsb + row * 512;
            const int sw  = SWZ(row);
#pragma unroll
            for (int q2 = 0; q2 < 4; ++q2) {
                const float4 v0 = x[2 * q2], v1 = x[2 * q2 + 1];
                bf16x8 o;
                o[0] = f2bf(v0.x * rinv); o[1] = f2bf(v0.y * rinv);
                o[2] = f2bf(v0.z * rinv); o[3] = f2bf(v0.w * rinv);
                o[4] = f2bf(v1.x * rinv); o[5] = f2bf(v1.y * rinv);
                o[6] = f2bf(v1.z * rinv); o[7] = f2bf(v1.w * rinv);
                *reinterpret_cast<bf16x8*>(dstrow + ((ecolB + q2 * 16) ^ sw)) = o;
            }
        }
    }
    __syncthreads();

    // ---- cache this wave's A fragments: rows [wr*32, +32) -> a[2][8] = 64 VGPR ----
    bf16x8 a[2][8];
#pragma unroll
    for (int i = 0; i < 2; ++i) {
        const int row  = wr * 32 + i * 16 + ln;
        const char* rp = ldsb + row * 512;
        const int sw   = SWZ(row);
#pragma unroll
        for (int kk = 0; kk < 8; ++kk)
            a[i][kk] = *reinterpret_cast<const bf16x8*>(rp + ((kk * 64 + g * 16) ^ sw));
    }
    __syncthreads();  // all a[] reads done; full drain -> vmcnt clean before DMA pipeline

    // ---- issue DMA for tiles 0 and 1 (wave stages rows [wave*8, +8) of each 32-row tile) ----
#pragma unroll
    for (int t0 = 0; t0 < 2; ++t0) {
        const char* gtile = gT + (size_t)t0 * 32 * 512;
        char* dst = ldsb + t0 * 16384 + wave * 4096;
#pragma unroll
        for (int r2 = 0; r2 < 4; ++r2) {
            const int L  = r2 * 1024 + (lane << 4);
            const int lr = L >> 9, inrow = L & 511;  // local row within the wave's 8
            __builtin_amdgcn_global_load_lds(
                (const u32*)(gtile + (size_t)(wave * 8 + lr) * 512 + (inrow ^ SWZ(lr))),
                (u32*)(dst + r2 * 1024), 16, 0, 0);
        }
    }

    float rs[2][4];  // rowsum of exp(2S) over this wave's cols
    float dg[2][4];  // diagonal 2*S term
#pragma unroll
    for (int i = 0; i < 2; ++i)
#pragma unroll
        for (int r = 0; r < 4; ++r) { rs[i][r] = 0.f; dg[i][r] = 0.f; }

    for (int t = 0; t < 16; ++t) {  // 16 tiles of 32 T-rows
        // ---- data-ready: my 4 tile-t loads landed (t+1's 4 may stay in flight), then all ----
        if (t < 15) asm volatile("s_waitcnt vmcnt(4)" ::: "memory");
        else        asm volatile("s_waitcnt vmcnt(0)" ::: "memory");
        __builtin_amdgcn_s_barrier();
        __builtin_amdgcn_sched_barrier(0);

        // ---- consume tile t: 8 ds_read + 16 MFMA ----
        const char* rp = ldsb + (t & 1) * 16384 + (wc * 16 + ln) * 512;
        const int sw   = SWZ(ln);  // wc*16 is 0 mod 8
        f32x4 acc[2] = {(f32x4){0.f, 0.f, 0.f, 0.f}, (f32x4){0.f, 0.f, 0.f, 0.f}};
        __builtin_amdgcn_s_setprio(1);
#pragma unroll
        for (int kk = 0; kk < 8; ++kk) {
            const bf16x8 bb = *reinterpret_cast<const bf16x8*>(rp + ((kk * 64 + g * 16) ^ sw));
            acc[0] = __builtin_amdgcn_mfma_f32_16x16x32_bf16(a[0][kk], bb, acc[0], 0, 0, 0);
            acc[1] = __builtin_amdgcn_mfma_f32_16x16x32_bf16(a[1][kk], bb, acc[1], 0, 0, 0);
        }
        __builtin_amdgcn_s_setprio(0);

        // ---- fused epilogue: exp(2*S) partial rowsum + diagonal grab ----
        const int gcol = t * 32 + wc * 16 + ln;
#pragma unroll
        for (int i = 0; i < 2; ++i) {
            const int grow = rb * 64 + wr * 32 + i * 16 + g * 4;  // + r
#pragma unroll
            for (int r = 0; r < 4; ++r) {
                const float s2 = acc[i][r] * 2.0f;  // sim / TEMPERATURE
                rs[i][r] += __expf(s2);
                if (gcol == grow + r) dg[i][r] += s2;
            }
        }

        // ---- consume-done barrier, then overwrite buf[t&1] with tile t+2 ----
        __builtin_amdgcn_s_barrier();
        __builtin_amdgcn_sched_barrier(0);
        if (t < 14) {
            const char* gtile = gT + (size_t)(t + 2) * 32 * 512;
            char* dst = ldsb + (t & 1) * 16384 + wave * 4096;
#pragma unroll
            for (int r2 = 0; r2 < 4; ++r2) {
                const int L  = r2 * 1024 + (lane << 4);
                const int lr = L >> 9, inrow = L & 511;
                __builtin_amdgcn_global_load_lds(
                    (const u32*)(gtile + (size_t)(wave * 8 + lr) * 512 + (inrow ^ SWZ(lr))),
                    (u32*)(dst + r2 * 1024), 16, 0, 0);
            }
        }
    }

    // ---- per-row completion: combine the two wc-waves' exp-sums BEFORE log ----
#pragma unroll
    for (int i = 0; i < 2; ++i)
#pragma unroll
        for (int r = 0; r < 4; ++r) {
            float v = rs[i][r];
            float d = dg[i][r];
#pragma unroll
            for (int m = 1; m < 16; m <<= 1) {  // reduce the 16 column-lanes
                v += __shfl_xor(v, m);
                d += __shfl_xor(d, m);
            }
            if (ln == 0) {
                const int rl = wr * 32 + i * 16 + g * 4 + r;  // local row 0..63
                vred[rl * 2 + wc] = v;
                dred[rl * 2 + wc] = d;
            }
        }
    __syncthreads();

    if (tid < 64) {
        const float vv = vred[tid * 2] + vred[tid * 2 + 1];
        const float dd = dred[tid * 2] + dred[tid * 2 + 1];
        float lsum = logf(vv) - dd;
#pragma unroll
        for (int m = 1; m < 64; m <<= 1) lsum += __shfl_xor(lsum, m);
        if (tid == 0) partials[i0] = lsum;
    }
}

// ---------------- Pass 3: final deterministic reduce (512 partials) ----------------
__global__ __launch_bounds__(256) void final_reduce(const float* __restrict__ partials,
                                                    float* __restrict__ out) {
    const int t = threadIdx.x;
    float v = partials[t] + partials[t + 256];
#pragma unroll
    for (int m = 1; m < 64; m <<= 1) v += __shfl_xor(v, m);
    __shared__ float red[4];
    if ((t & 63) == 0) red[t >> 6] = v;
    __syncthreads();
    if (t == 0) out[0] = (red[0] + red[1] + red[2] + red[3]) * (1.0f / 32768.0f);
}

extern "C" void kernel_launch(void* const* d_in, const int* in_sizes, int n_in,
                              void* d_out, int out_size, void* d_ws, size_t ws_size,
                              hipStream_t stream) {
    const float* vis = (const float*)d_in[0];
    const float* txt = (const float*)d_in[1];

    unsigned short* Tn = (unsigned short*)d_ws;                             // 16.8 MB
    float* partials    = (float*)((char*)d_ws + (size_t)BB * CC * DD * 2);  // 512 floats
    float* out         = (float*)d_out;

    norm_rows<<<8192, 256, 0, stream>>>(txt, Tn);
    gemm_loss<<<512, 256, 0, stream>>>(vis, Tn, partials);
    final_reduce<<<1, 256, 0, stream>>>(partials, out);
}

// Round 10
// 39.699 us; speedup vs baseline: 1.2765x; 1.0193x over previous
//
#include <hip/hip_runtime.h>
#include <hip/hip_bf16.h>

// Problem constants
#define BB 64
#define CC 512
#define DD 256
// loss = mean_{b,c} [ log(sum_k exp(2*S_bck)) - 2*S_bcc ],  S = Vn . Tn^T (rows L2-normalized)

typedef __attribute__((ext_vector_type(8))) short bf16x8;  // 8 bf16 = 4 VGPRs
typedef __attribute__((ext_vector_type(4))) float f32x4;
typedef unsigned int u32;

#define SWZ(r) (((r) & 7) << 4)

__device__ inline short f2bf(float f) {
    union { __hip_bfloat16 h; short s; } cv;
    cv.h = __float2bfloat16(f);
    return cv.s;
}

// ---------------- Pass 1: L2-normalize T rows (fp32 in -> bf16 out), ~85% HBM ----------------
__global__ __launch_bounds__(256) void norm_rows(const float* __restrict__ in,
                                                 unsigned short* __restrict__ out) {
    const int row  = blockIdx.x * 4 + (threadIdx.x >> 6);
    const int lane = threadIdx.x & 63;
    const float4 x = reinterpret_cast<const float4*>(in)[(size_t)row * 64 + lane];
    float ss = x.x * x.x + x.y * x.y + x.z * x.z + x.w * x.w;
#pragma unroll
    for (int off = 32; off; off >>= 1) ss += __shfl_xor(ss, off);
    const float r = 1.0f / fmaxf(sqrtf(ss), 1e-12f);
    ushort4 o;
    o.x = (unsigned short)f2bf(x.x * r);
    o.y = (unsigned short)f2bf(x.y * r);
    o.z = (unsigned short)f2bf(x.z * r);
    o.w = (unsigned short)f2bf(x.w * r);
    reinterpret_cast<ushort4*>(out)[(size_t)row * 64 + lane] = o;
}

// ---------------- Pass 2: fused V-norm + GEMM + loss — VMEM-VOLUME-MINIMIZED ----------------
// 256 blocks = 64 batches x 4 row-blocks of 128 V-rows; 512 threads (8 waves: wr=wave>>1
// owns a 32-row band, wc=wave&1 owns 16 of each 32-col tile). Tn staging redundancy drops
// 8x -> 4x (gemm VMEM 168 MB -> 100 MB; staging-BW-bound per R9 analysis).
// B: 16 tiles x 32 Tn rows (16 KB), THREE buffers, DMA issued 2 tiles ahead, ONE barrier
// per tile, counted s_waitcnt vmcnt(2) (prefetch never drained mid-loop).
// A: 128 fp32 V rows normalized in prologue (read once), cached in regs a[2][8].
__global__ __launch_bounds__(512, 2) void gemm_loss(const float* __restrict__ V,
                                                    const unsigned short* __restrict__ Tn,
                                                    float* __restrict__ partials) {
    __shared__ char ldsb[65536];  // prologue: A staging 128x512B; loop: 3x16KB B buffers
    __shared__ float vred[256];   // [128 rows][2 wc] partial exp-sums
    __shared__ float dred[256];   // [128 rows][2 wc] partial diag terms
    __shared__ float red2[2];

    // XCD-aware remap: the 4 rb-blocks of one batch land on one XCD (Tn panel L2 reuse)
    const int i0    = blockIdx.x;       // 0..255
    const int inner = i0 & 63;
    const int b     = (inner & 7) * 8 + (inner >> 3);  // bijective over 0..63
    const int rb    = i0 >> 6;                         // 0..3

    const int tid  = threadIdx.x;  // 0..511
    const int lane = tid & 63;
    const int wave = tid >> 6;     // 0..7
    const int wr   = wave >> 1;    // 32-row band
    const int wc   = wave & 1;     // 16-col half of each 32-col tile
    const int g    = lane >> 4;    // k-group 0..3
    const int ln   = lane & 15;

    const float* gV = V + (size_t)b * (CC * DD) + (size_t)rb * 128 * DD;
    const char*  gT = reinterpret_cast<const char*>(Tn + (size_t)b * (CC * DD));  // 512 B rows

    // ---- A prologue: load 128 fp32 V rows, L2-normalize, write bf16 swizzled to ldsb ----
    {
        const int rrow  = tid >> 3;        // 8 threads/row, 64 rows/pass
        const int ecolB = (tid & 7) * 64;  // byte offset of this thread's 32 bf16 elems
#pragma unroll
        for (int p = 0; p < 2; ++p) {
            const int row = p * 64 + rrow;
            const float4* src =
                reinterpret_cast<const float4*>(gV + (size_t)row * DD) + (tid & 7) * 8;
            float4 x[8];
#pragma unroll
            for (int q = 0; q < 8; ++q) x[q] = src[q];
            float ss = 0.f;
#pragma unroll
            for (int q = 0; q < 8; ++q)
                ss += x[q].x * x[q].x + x[q].y * x[q].y + x[q].z * x[q].z + x[q].w * x[q].w;
            ss += __shfl_xor(ss, 1);
            ss += __shfl_xor(ss, 2);
            ss += __shfl_xor(ss, 4);  // 8 lanes own the row
            const float rinv = 1.0f / fmaxf(sqrtf(ss), 1e-12f);
            char* dstrow = ldsb + row * 512;
            const int sw = SWZ(row);
#pragma unroll
            for (int q2 = 0; q2 < 4; ++q2) {
                const float4 v0 = x[2 * q2], v1 = x[2 * q2 + 1];
                bf16x8 o;
                o[0] = f2bf(v0.x * rinv); o[1] = f2bf(v0.y * rinv);
                o[2] = f2bf(v0.z * rinv); o[3] = f2bf(v0.w * rinv);
                o[4] = f2bf(v1.x * rinv); o[5] = f2bf(v1.y * rinv);
                o[6] = f2bf(v1.z * rinv); o[7] = f2bf(v1.w * rinv);
                *reinterpret_cast<bf16x8*>(dstrow + ((ecolB + q2 * 16) ^ sw)) = o;
            }
        }
    }
    __syncthreads();

    // ---- cache this wave's A fragments: rows [wr*32, +32) -> a[2][8] = 64 VGPR ----
    bf16x8 a[2][8];
#pragma unroll
    for (int i = 0; i < 2; ++i) {
        const int row  = wr * 32 + i * 16 + ln;
        const char* rp = ldsb + row * 512;
        const int sw   = SWZ(row);
#pragma unroll
        for (int kk = 0; kk < 8; ++kk)
            a[i][kk] = *reinterpret_cast<const bf16x8*>(rp + ((kk * 64 + g * 16) ^ sw));
    }
    __syncthreads();  // implicit vmcnt(0): all clean; ldsb now free for B buffers

    // ---- DMA stage helper: tile t (32 Tn rows, 16 KB); this wave stages rows [wave*4,+4) ----
    auto stage = [&](int t) {
        const char* gtile = gT + (size_t)t * 16384;
        char* dst = ldsb + (t % 3) * 16384 + wave * 2048;
#pragma unroll
        for (int r2 = 0; r2 < 2; ++r2) {
            const int L   = r2 * 1024 + (lane << 4);
            const int lr  = L >> 9;           // 0..3 local row
            const int row = wave * 4 + lr;    // row within tile
            const int inrow = L & 511;
            __builtin_amdgcn_global_load_lds(
                (const u32*)(gtile + (size_t)row * 512 + (inrow ^ SWZ(row))),
                (u32*)(dst + r2 * 1024), 16, 0, 0);
        }
    };
    stage(0);
    stage(1);  // 4 loads in flight per wave

    float rs[2][4];  // rowsum of exp(2S) over this wave's cols
    float dg[2][4];  // diagonal 2*S term
#pragma unroll
    for (int i = 0; i < 2; ++i)
#pragma unroll
        for (int r = 0; r < 4; ++r) { rs[i][r] = 0.f; dg[i][r] = 0.f; }

    for (int t = 0; t < 16; ++t) {  // NOT unrolled (register pressure)
        // my 2 tile-t loads landed (tile t+1's 2 stay in flight), then all waves' did
        if (t < 15) asm volatile("s_waitcnt vmcnt(2)" ::: "memory");
        else        asm volatile("s_waitcnt vmcnt(0)" ::: "memory");
        __builtin_amdgcn_s_barrier();
        __builtin_amdgcn_sched_barrier(0);
        // stage t+2 into buf[(t+2)%3] = buf[(t-1)%3]; barrier above proved all waves
        // finished consuming tile t-1 -> no WAR race with a single barrier per tile
        if (t < 14) stage(t + 2);

        // ---- consume tile t: 8 ds_read + 16 MFMA ----
        const char* rp = ldsb + (t % 3) * 16384 + (wc * 16 + ln) * 512;
        const int sw   = SWZ(ln);  // wc*16 is 0 mod 8
        f32x4 acc[2] = {(f32x4){0.f, 0.f, 0.f, 0.f}, (f32x4){0.f, 0.f, 0.f, 0.f}};
        __builtin_amdgcn_s_setprio(1);
#pragma unroll
        for (int kk = 0; kk < 8; ++kk) {
            const bf16x8 bb = *reinterpret_cast<const bf16x8*>(rp + ((kk * 64 + g * 16) ^ sw));
            acc[0] = __builtin_amdgcn_mfma_f32_16x16x32_bf16(a[0][kk], bb, acc[0], 0, 0, 0);
            acc[1] = __builtin_amdgcn_mfma_f32_16x16x32_bf16(a[1][kk], bb, acc[1], 0, 0, 0);
        }
        __builtin_amdgcn_s_setprio(0);

        // ---- fused epilogue: exp(2*S) partial rowsum + diagonal grab ----
        const int gcol = t * 32 + wc * 16 + ln;
#pragma unroll
        for (int i = 0; i < 2; ++i) {
            const int grow = rb * 128 + wr * 32 + i * 16 + g * 4;  // + r
#pragma unroll
            for (int r = 0; r < 4; ++r) {
                const float s2 = acc[i][r] * 2.0f;  // sim / TEMPERATURE
                rs[i][r] += __expf(s2);
                if (gcol == grow + r) dg[i][r] += s2;
            }
        }
    }

    // ---- per-row completion: combine the two wc-waves' exp-sums BEFORE log ----
#pragma unroll
    for (int i = 0; i < 2; ++i)
#pragma unroll
        for (int r = 0; r < 4; ++r) {
            float v = rs[i][r];
            float d = dg[i][r];
#pragma unroll
            for (int m = 1; m < 16; m <<= 1) {  // reduce the 16 column-lanes
                v += __shfl_xor(v, m);
                d += __shfl_xor(d, m);
            }
            if (ln == 0) {
                const int rl = wr * 32 + i * 16 + g * 4 + r;  // local row 0..127
                vred[rl * 2 + wc] = v;
                dred[rl * 2 + wc] = d;
            }
        }
    __syncthreads();

    if (tid < 128) {
        const float vv = vred[tid * 2] + vred[tid * 2 + 1];
        const float dd = dred[tid * 2] + dred[tid * 2 + 1];
        float lsum = logf(vv) - dd;
#pragma unroll
        for (int m = 1; m < 64; m <<= 1) lsum += __shfl_xor(lsum, m);
        if (lane == 0) red2[wave] = lsum;  // waves 0,1
    }
    __syncthreads();
    if (tid == 0) partials[i0] = red2[0] + red2[1];
}

// ---------------- Pass 3: final deterministic reduce (256 partials) ----------------
__global__ __launch_bounds__(256) void final_reduce(const float* __restrict__ partials,
                                                    float* __restrict__ out) {
    const int t = threadIdx.x;
    float v = partials[t];
#pragma unroll
    for (int m = 1; m < 64; m <<= 1) v += __shfl_xor(v, m);
    __shared__ float red[4];
    if ((t & 63) == 0) red[t >> 6] = v;
    __syncthreads();
    if (t == 0) out[0] = (red[0] + red[1] + red[2] + red[3]) * (1.0f / 32768.0f);
}

extern "C" void kernel_launch(void* const* d_in, const int* in_sizes, int n_in,
                              void* d_out, int out_size, void* d_ws, size_t ws_size,
                              hipStream_t stream) {
    const float* vis = (const float*)d_in[0];
    const float* txt = (const float*)d_in[1];

    unsigned short* Tn = (unsigned short*)d_ws;                             // 16.8 MB
    float* partials    = (float*)((char*)d_ws + (size_t)BB * CC * DD * 2);  // 256 floats
    float* out         = (float*)d_out;

    norm_rows<<<8192, 256, 0, stream>>>(txt, Tn);
    gemm_loss<<<256, 512, 0, stream>>>(vis, Tn, partials);
    final_reduce<<<1, 256, 0, stream>>>(partials, out);
}

// Round 11
// 35.503 us; speedup vs baseline: 1.4274x; 1.1182x over previous
//
#include <hip/hip_runtime.h>
#include <hip/hip_bf16.h>

// Problem constants
#define BB 64
#define CC 512
#define DD 256
// loss = mean_{b,c} [ log(sum_k exp(2*S_bck)) - 2*S_bcc ],  S = Vn . Tn^T (rows L2-normalized)

typedef __attribute__((ext_vector_type(8))) short bf16x8;  // 8 bf16 = 4 VGPRs
typedef __attribute__((ext_vector_type(4))) float f32x4;
typedef unsigned int u32;

#define SWZ(r) (((r) & 7) << 4)

__device__ inline short f2bf(float f) {
    union { __hip_bfloat16 h; short s; } cv;
    cv.h = __float2bfloat16(f);
    return cv.s;
}

// ---------------- Pass 1: L2-normalize T rows (fp32 in -> bf16 out), ~85% HBM ----------------
__global__ __launch_bounds__(256) void norm_rows(const float* __restrict__ in,
                                                 unsigned short* __restrict__ out) {
    const int row  = blockIdx.x * 4 + (threadIdx.x >> 6);
    const int lane = threadIdx.x & 63;
    const float4 x = reinterpret_cast<const float4*>(in)[(size_t)row * 64 + lane];
    float ss = x.x * x.x + x.y * x.y + x.z * x.z + x.w * x.w;
#pragma unroll
    for (int off = 32; off; off >>= 1) ss += __shfl_xor(ss, off);
    const float r = 1.0f / fmaxf(sqrtf(ss), 1e-12f);
    ushort4 o;
    o.x = (unsigned short)f2bf(x.x * r);
    o.y = (unsigned short)f2bf(x.y * r);
    o.z = (unsigned short)f2bf(x.z * r);
    o.w = (unsigned short)f2bf(x.w * r);
    reinterpret_cast<ushort4*>(out)[(size_t)row * 64 + lane] = o;
}

// ---------------- Pass 2: fused V-norm + GEMM + loss — FEWER PHASES, DEEPER PIPELINE ----
// 256 blocks = 64 batches x 4 row-blocks of 128 V-rows; 512 threads (8 waves: wr=wave>>1
// owns a 32-row band, wc=wave&1 owns 32 of each 64-col tile). 8 tile-phases (64 T-rows,
// 32 KB each), FOUR LDS buffers, prefetch depth 3 (12 gload_lds in flight, counted
// s_waitcnt vmcnt(8), never drained mid-loop). One barrier per tile: stage(t+3) lands in
// buf[(t+3)%4]=buf[(t-1)%4], and barrier t proves all waves consumed t-1 (WAR-safe).
// Per tile per wave: 16 ds_read_b128 + 32 MFMA + 16 exp. A: 128 fp32 V rows normalized
// in prologue (read once from HBM), cached in regs a[2][8].
__global__ __launch_bounds__(512, 1) void gemm_loss(const float* __restrict__ V,
                                                    const unsigned short* __restrict__ Tn,
                                                    float* __restrict__ partials) {
    extern __shared__ char lds[];  // 4 x 32KB tile buffers (prologue: A staging in [0,64K))
    float* vred = reinterpret_cast<float*>(lds + 131072);  // [128 rows][2 wc]
    float* dred = vred + 256;                              // [128 rows][2 wc]
    float* red2 = dred + 256;                              // [2]

    // XCD-aware remap: the 4 rb-blocks of one batch land on one XCD (Tn panel L2 reuse)
    const int i0    = blockIdx.x;  // 0..255
    const int inner = i0 & 63;
    const int b     = (inner & 7) * 8 + (inner >> 3);  // bijective over 0..63
    const int rb    = i0 >> 6;                         // 0..3

    const int tid  = threadIdx.x;  // 0..511
    const int lane = tid & 63;
    const int wave = tid >> 6;     // 0..7
    const int wr   = wave >> 1;    // 32-row band of the 128 block rows
    const int wc   = wave & 1;     // 32-col half of each 64-col tile
    const int g    = lane >> 4;    // k-group 0..3
    const int ln   = lane & 15;

    const float* gV = V + (size_t)b * (CC * DD) + (size_t)rb * 128 * DD;
    const char*  gT = reinterpret_cast<const char*>(Tn + (size_t)b * (CC * DD));  // 512 B rows

    // ---- A prologue: load 128 fp32 V rows, L2-normalize, write bf16 swizzled to lds ----
    {
        const int rrow  = tid >> 3;        // 8 threads/row, 64 rows/pass
        const int ecolB = (tid & 7) * 64;  // byte offset of this thread's 32 bf16 elems
#pragma unroll
        for (int p = 0; p < 2; ++p) {
            const int row = p * 64 + rrow;
            const float4* src =
                reinterpret_cast<const float4*>(gV + (size_t)row * DD) + (tid & 7) * 8;
            float4 x[8];
#pragma unroll
            for (int q = 0; q < 8; ++q) x[q] = src[q];
            float ss = 0.f;
#pragma unroll
            for (int q = 0; q < 8; ++q)
                ss += x[q].x * x[q].x + x[q].y * x[q].y + x[q].z * x[q].z + x[q].w * x[q].w;
            ss += __shfl_xor(ss, 1);
            ss += __shfl_xor(ss, 2);
            ss += __shfl_xor(ss, 4);  // 8 lanes own the row
            const float rinv = 1.0f / fmaxf(sqrtf(ss), 1e-12f);
            char* dstrow = lds + row * 512;
            const int sw = SWZ(row);
#pragma unroll
            for (int q2 = 0; q2 < 4; ++q2) {
                const float4 v0 = x[2 * q2], v1 = x[2 * q2 + 1];
                bf16x8 o;
                o[0] = f2bf(v0.x * rinv); o[1] = f2bf(v0.y * rinv);
                o[2] = f2bf(v0.z * rinv); o[3] = f2bf(v0.w * rinv);
                o[4] = f2bf(v1.x * rinv); o[5] = f2bf(v1.y * rinv);
                o[6] = f2bf(v1.z * rinv); o[7] = f2bf(v1.w * rinv);
                *reinterpret_cast<bf16x8*>(dstrow + ((ecolB + q2 * 16) ^ sw)) = o;
            }
        }
    }
    __syncthreads();

    // ---- cache this wave's A fragments: rows [wr*32, +32) -> a[2][8] = 64 VGPR ----
    bf16x8 a[2][8];
#pragma unroll
    for (int i = 0; i < 2; ++i) {
        const int row  = wr * 32 + i * 16 + ln;
        const char* rp = lds + row * 512;
        const int sw   = SWZ(row);
#pragma unroll
        for (int kk = 0; kk < 8; ++kk)
            a[i][kk] = *reinterpret_cast<const bf16x8*>(rp + ((kk * 64 + g * 16) ^ sw));
    }
    __syncthreads();  // implicit vmcnt(0): clean counter; lds free for tile buffers

    // ---- DMA stage: tile t = 64 Tn rows (32 KB) -> buf[t%4]; wave stages rows [wave*8,+8) ----
    auto stage = [&](int t) {
        const char* gtile = gT + (size_t)t * 32768;
        char* dst = lds + (t & 3) * 32768 + wave * 4096;
#pragma unroll
        for (int r2 = 0; r2 < 4; ++r2) {
            const int L   = r2 * 1024 + (lane << 4);
            const int lr  = L >> 9;  // 0..7 local row (within wave's 8)
            const int row = wave * 8 + lr;
            const int inrow = L & 511;
            __builtin_amdgcn_global_load_lds(
                (const u32*)(gtile + (size_t)row * 512 + (inrow ^ SWZ(row))),
                (u32*)(dst + r2 * 1024), 16, 0, 0);
        }
    };
    stage(0);
    stage(1);
    stage(2);  // 12 loads in flight per wave (depth 3)

    float rs[2][4];  // rowsum of exp(2S) over this wave's cols, per (i, r)
    float dg[2][4];  // diagonal 2*S term
#pragma unroll
    for (int i = 0; i < 2; ++i)
#pragma unroll
        for (int r = 0; r < 4; ++r) { rs[i][r] = 0.f; dg[i][r] = 0.f; }

    for (int t = 0; t < 8; ++t) {  // NOT unrolled (register pressure)
        // counted wait: my 4 tile-t loads landed (t+1,t+2's 8 stay in flight); then all waves'
        if (t < 6)      asm volatile("s_waitcnt vmcnt(8)" ::: "memory");
        else if (t == 6) asm volatile("s_waitcnt vmcnt(4)" ::: "memory");
        else            asm volatile("s_waitcnt vmcnt(0)" ::: "memory");
        __builtin_amdgcn_s_barrier();
        __builtin_amdgcn_sched_barrier(0);
        // stage t+3 into buf[(t+3)%4] = buf[(t-1)%4]; the barrier above proved every wave
        // finished consuming tile t-1 -> WAR-safe with ONE barrier per tile
        if (t < 5) stage(t + 3);

        // ---- consume tile t: 16 ds_read + 32 MFMA (acc 2x2 fragments = 32x32 output) ----
        const char* bufp = lds + (t & 3) * 32768;
        const int row0 = wc * 32 + ln;        // jc=0 B-row
        const int row1 = wc * 32 + 16 + ln;   // jc=1 B-row
        const char* rp0 = bufp + row0 * 512;
        const char* rp1 = bufp + row1 * 512;
        const int sw0 = SWZ(row0), sw1 = SWZ(row1);
        f32x4 acc[2][2];
#pragma unroll
        for (int i = 0; i < 2; ++i)
#pragma unroll
            for (int j = 0; j < 2; ++j) acc[i][j] = (f32x4){0.f, 0.f, 0.f, 0.f};
        __builtin_amdgcn_s_setprio(1);
#pragma unroll
        for (int kk = 0; kk < 8; ++kk) {
            const int ko = kk * 64 + g * 16;
            const bf16x8 b0 = *reinterpret_cast<const bf16x8*>(rp0 + (ko ^ sw0));
            const bf16x8 b1 = *reinterpret_cast<const bf16x8*>(rp1 + (ko ^ sw1));
            acc[0][0] = __builtin_amdgcn_mfma_f32_16x16x32_bf16(a[0][kk], b0, acc[0][0], 0, 0, 0);
            acc[1][0] = __builtin_amdgcn_mfma_f32_16x16x32_bf16(a[1][kk], b0, acc[1][0], 0, 0, 0);
            acc[0][1] = __builtin_amdgcn_mfma_f32_16x16x32_bf16(a[0][kk], b1, acc[0][1], 0, 0, 0);
            acc[1][1] = __builtin_amdgcn_mfma_f32_16x16x32_bf16(a[1][kk], b1, acc[1][1], 0, 0, 0);
        }
        __builtin_amdgcn_s_setprio(0);

        // ---- fused epilogue: exp(2*S) partial rowsum; diagonal gated to its 2 tiles ----
        if ((t >> 1) == rb) {
#pragma unroll
            for (int i = 0; i < 2; ++i) {
                const int grow = rb * 128 + wr * 32 + i * 16 + g * 4;  // + r
#pragma unroll
                for (int j = 0; j < 2; ++j) {
                    const int gcol = t * 64 + wc * 32 + j * 16 + ln;
#pragma unroll
                    for (int r = 0; r < 4; ++r) {
                        const float s2 = acc[i][j][r] * 2.0f;
                        rs[i][r] += __expf(s2);
                        if (gcol == grow + r) dg[i][r] += s2;
                    }
                }
            }
        } else {
#pragma unroll
            for (int i = 0; i < 2; ++i)
#pragma unroll
                for (int j = 0; j < 2; ++j)
#pragma unroll
                    for (int r = 0; r < 4; ++r) rs[i][r] += __expf(acc[i][j][r] * 2.0f);
        }
    }

    // ---- per-row completion: combine the two wc-halves' exp-sums BEFORE log ----
#pragma unroll
    for (int i = 0; i < 2; ++i)
#pragma unroll
        for (int r = 0; r < 4; ++r) {
            float v = rs[i][r];
            float d = dg[i][r];
#pragma unroll
            for (int m = 1; m < 16; m <<= 1) {  // reduce the 16 column-lanes
                v += __shfl_xor(v, m);
                d += __shfl_xor(d, m);
            }
            if (ln == 0) {
                const int rl = wr * 32 + i * 16 + g * 4 + r;  // local row 0..127
                vred[rl * 2 + wc] = v;
                dred[rl * 2 + wc] = d;
            }
        }
    __syncthreads();

    if (tid < 128) {
        const float vv = vred[tid * 2] + vred[tid * 2 + 1];
        const float dd = dred[tid * 2] + dred[tid * 2 + 1];
        float lsum = logf(vv) - dd;
#pragma unroll
        for (int m = 1; m < 64; m <<= 1) lsum += __shfl_xor(lsum, m);
        if (lane == 0) red2[wave] = lsum;  // waves 0,1
    }
    __syncthreads();
    if (tid == 0) partials[i0] = red2[0] + red2[1];
}

// ---------------- Pass 3: final deterministic reduce (256 partials) ----------------
__global__ __launch_bounds__(256) void final_reduce(const float* __restrict__ partials,
                                                    float* __restrict__ out) {
    const int t = threadIdx.x;
    float v = partials[t];
#pragma unroll
    for (int m = 1; m < 64; m <<= 1) v += __shfl_xor(v, m);
    __shared__ float red[4];
    if ((t & 63) == 0) red[t >> 6] = v;
    __syncthreads();
    if (t == 0) out[0] = (red[0] + red[1] + red[2] + red[3]) * (1.0f / 32768.0f);
}

extern "C" void kernel_launch(void* const* d_in, const int* in_sizes, int n_in,
                              void* d_out, int out_size, void* d_ws, size_t ws_size,
                              hipStream_t stream) {
    const float* vis = (const float*)d_in[0];
    const float* txt = (const float*)d_in[1];

    unsigned short* Tn = (unsigned short*)d_ws;                             // 16.8 MB
    float* partials    = (float*)((char*)d_ws + (size_t)BB * CC * DD * 2);  // 256 floats
    float* out         = (float*)d_out;

    const int lds_bytes = 131072 + 256 * 4 + 256 * 4 + 16;
    hipFuncSetAttribute((const void*)gemm_loss, hipFuncAttributeMaxDynamicSharedMemorySize,
                        lds_bytes);

    norm_rows<<<8192, 256, 0, stream>>>(txt, Tn);
    gemm_loss<<<256, 512, lds_bytes, stream>>>(vis, Tn, partials);
    final_reduce<<<1, 256, 0, stream>>>(partials, out);
}